// Round 1
// baseline (355.506 us; speedup 1.0000x reference)
//
#include <hip/hip_runtime.h>
#include <stdint.h>

#define NROW 8192
#define MCOL 8192
#define DH 64

// scale * log2(e): softmax computed as exp2(s * SC2) / sum
#define SC2 0.18033688011112042f

typedef __attribute__((ext_vector_type(8))) short short8;   // 8 bf16 (4 VGPRs)
typedef __attribute__((ext_vector_type(4))) float f32x4;

__device__ __forceinline__ short8 ldb8(const uint16_t* p) {
    return *reinterpret_cast<const short8*>(p);
}

__device__ __forceinline__ uint16_t f2bf(float f) {
    uint32_t u = __builtin_bit_cast(uint32_t, f);
    uint32_t r = (u + 0x7fffu + ((u >> 16) & 1u)) >> 16;
    return (uint16_t)r;
}

// ---------------- k_prep: Q,K -> bf16 ; V -> bf16 transposed Vt[d][c] ---------
__global__ __launch_bounds__(256) void k_prep(const float* __restrict__ Q,
                                              const float* __restrict__ K,
                                              const float* __restrict__ V,
                                              uint16_t* __restrict__ Qb,
                                              uint16_t* __restrict__ Kb,
                                              uint16_t* __restrict__ Vt) {
    int b = blockIdx.x, t = threadIdx.x;
    if (b < 128) {
        // transpose V rows [c0, c0+64) into Vt[dv][c]
        __shared__ float tile[64][65];
        int c0 = b * 64;
#pragma unroll
        for (int it = 0; it < 4; ++it) {
            int r = it * 16 + (t >> 4);
            int col = (t & 15) * 4;
            f32x4 v = *reinterpret_cast<const f32x4*>(V + (size_t)(c0 + r) * DH + col);
            tile[r][col + 0] = v[0]; tile[r][col + 1] = v[1];
            tile[r][col + 2] = v[2]; tile[r][col + 3] = v[3];
        }
        __syncthreads();
        int dv = t >> 2, cs = (t & 3) * 16;
        short8 o0, o1;
#pragma unroll
        for (int i = 0; i < 8; ++i) o0[i] = (short)f2bf(tile[cs + i][dv]);
#pragma unroll
        for (int i = 0; i < 8; ++i) o1[i] = (short)f2bf(tile[cs + 8 + i][dv]);
        *reinterpret_cast<short8*>(Vt + (size_t)dv * MCOL + c0 + cs) = o0;
        *reinterpret_cast<short8*>(Vt + (size_t)dv * MCOL + c0 + cs + 8) = o1;
    } else {
        const float* src; uint16_t* dst; int base;
        if (b < 640) { base = (b - 128) * 1024 + t * 4; src = Q; dst = Qb; }
        else         { base = (b - 640) * 1024 + t * 4; src = K; dst = Kb; }
        f32x4 v = *reinterpret_cast<const f32x4*>(src + base);
        uint64_t pk = (uint64_t)f2bf(v[0]) | ((uint64_t)f2bf(v[1]) << 16) |
                      ((uint64_t)f2bf(v[2]) << 32) | ((uint64_t)f2bf(v[3]) << 48);
        *reinterpret_cast<uint64_t*>(dst + base) = pk;
    }
}

// ---------------- k_pass1: row sums of masked exp + mask bit-packing ----------
__global__ __launch_bounds__(256) void k_pass1(const uint16_t* __restrict__ Qb,
                                               const uint16_t* __restrict__ Kb,
                                               const int* __restrict__ mask,
                                               unsigned long long* __restrict__ pm2,
                                               float* __restrict__ lpart,
                                               int nstrip, int write_pm) {
    int rb = blockIdx.x, s = blockIdx.y;
    int t = threadIdx.x, lane = t & 63, w = t >> 6;
    int rw = rb * 64 + w * 16;
    int li = lane & 15, g = lane >> 4;

    const uint16_t* qbase = Qb + (size_t)(rw + li) * DH + g * 8;
    short8 qa0 = ldb8(qbase), qa1 = ldb8(qbase + 32);

    float rs[4] = {0.f, 0.f, 0.f, 0.f};
    int steps = 128 / nstrip;

    for (int ccl = 0; ccl < steps; ++ccl) {
        int cc = s * steps + ccl;
        int c0 = cc * 64;
        // pack 16 rows x 64 cols of mask into one u64 per row (bit i = col c0+i)
        unsigned long long myw = 0ull;
#pragma unroll
        for (int rr = 0; rr < 16; ++rr) {
            int v = mask[(size_t)(rw + rr) * MCOL + c0 + lane];
            unsigned long long bl = __ballot(v != 0);
            if (lane == rr) myw = bl;
        }
        if (write_pm && lane < 16)
            pm2[(size_t)cc * NROW + rw + lane] = myw;
        unsigned long long w64[4];
#pragma unroll
        for (int j = 0; j < 4; ++j) w64[j] = __shfl(myw, g * 4 + j);

#pragma unroll
        for (int ct = 0; ct < 4; ++ct) {
            const uint16_t* kbase = Kb + (size_t)(c0 + ct * 16 + li) * DH + g * 8;
            short8 kb0 = ldb8(kbase), kb1 = ldb8(kbase + 32);
            f32x4 acc = {0.f, 0.f, 0.f, 0.f};
            acc = __builtin_amdgcn_mfma_f32_16x16x32_bf16(qa0, kb0, acc, 0, 0, 0);
            acc = __builtin_amdgcn_mfma_f32_16x16x32_bf16(qa1, kb1, acc, 0, 0, 0);
            int bi = ct * 16 + li;
#pragma unroll
            for (int j = 0; j < 4; ++j) {
                if (!((w64[j] >> bi) & 1ull))
                    rs[j] += __builtin_amdgcn_exp2f(acc[j] * SC2);
            }
        }
    }
    // reduce across the 16 lanes of each group (cols), write per-strip partials
#pragma unroll
    for (int j = 0; j < 4; ++j) {
        rs[j] += __shfl_xor(rs[j], 1);
        rs[j] += __shfl_xor(rs[j], 2);
        rs[j] += __shfl_xor(rs[j], 4);
        rs[j] += __shfl_xor(rs[j], 8);
    }
    if (li == 0) {
        f32x4 o = {rs[0], rs[1], rs[2], rs[3]};
        *reinterpret_cast<f32x4*>(lpart + (size_t)s * NROW + rw + g * 4) = o;
    }
}

// ---------------- k_pass2: probs + context partials ---------------------------
template <bool PACKED>
__global__ __launch_bounds__(256) void k_pass2(const uint16_t* __restrict__ Qb,
                                               const uint16_t* __restrict__ Kb,
                                               const uint16_t* __restrict__ Vt,
                                               const int* __restrict__ mask,
                                               const unsigned long long* __restrict__ pm2,
                                               const float* __restrict__ lpart,
                                               float* __restrict__ out_prob,
                                               float* __restrict__ ctx_out,
                                               int nstrip) {
    __shared__ uint16_t pt[4][1024];   // per-wave 16x64 bf16, XOR-swizzled
    int rb = blockIdx.x, s = blockIdx.y;
    int t = threadIdx.x, lane = t & 63, w = t >> 6;
    int rw = rb * 64 + w * 16;
    int li = lane & 15, g = lane >> 4;

    // 1/l for this group's 4 rows (sum strip partials)
    f32x4 lsum = {0.f, 0.f, 0.f, 0.f};
    for (int s2 = 0; s2 < nstrip; ++s2)
        lsum += *reinterpret_cast<const f32x4*>(lpart + (size_t)s2 * NROW + rw + g * 4);
    float rinv[4];
#pragma unroll
    for (int j = 0; j < 4; ++j) rinv[j] = 1.0f / lsum[j];

    const uint16_t* qbase = Qb + (size_t)(rw + li) * DH + g * 8;
    short8 qa0 = ldb8(qbase), qa1 = ldb8(qbase + 32);

    f32x4 ctx[4];
#pragma unroll
    for (int dt = 0; dt < 4; ++dt) ctx[dt] = (f32x4){0.f, 0.f, 0.f, 0.f};

    int steps = 128 / nstrip;
    for (int ccl = 0; ccl < steps; ++ccl) {
        int cc = s * steps + ccl;
        int c0 = cc * 64;
        unsigned long long w64[4];
        if (PACKED) {
            const unsigned long long* pmr = pm2 + (size_t)cc * NROW + rw;
#pragma unroll
            for (int j = 0; j < 4; ++j) w64[j] = pmr[g * 4 + j];
        }
#pragma unroll
        for (int ct = 0; ct < 4; ++ct) {
            const uint16_t* kbase = Kb + (size_t)(c0 + ct * 16 + li) * DH + g * 8;
            short8 kb0 = ldb8(kbase), kb1 = ldb8(kbase + 32);
            f32x4 acc = {0.f, 0.f, 0.f, 0.f};
            acc = __builtin_amdgcn_mfma_f32_16x16x32_bf16(qa0, kb0, acc, 0, 0, 0);
            acc = __builtin_amdgcn_mfma_f32_16x16x32_bf16(qa1, kb1, acc, 0, 0, 0);
            int bi = ct * 16 + li;
#pragma unroll
            for (int j = 0; j < 4; ++j) {
                int m = g * 4 + j;
                int bit;
                if (PACKED) bit = (int)((w64[j] >> bi) & 1ull);
                else        bit = (mask[(size_t)(rw + m) * MCOL + c0 + bi] != 0);
                float p = bit ? 0.0f : __builtin_amdgcn_exp2f(acc[j] * SC2) * rinv[j];
                out_prob[(size_t)(rw + m) * MCOL + c0 + bi] = p;
                int e = ((m << 6) + bi) ^ ((m & 7) << 3);
                pt[w][e] = f2bf(p);
            }
        }
        // PV: context += P(16x64) * V(64x64) via transposed-LDS A-fragments
#pragma unroll
        for (int kc = 0; kc < 2; ++kc) {
            int eidx = ((li << 6) + kc * 32 + (g << 3)) ^ ((li & 7) << 3);
            short8 pa = *reinterpret_cast<const short8*>(&pt[w][eidx]);
#pragma unroll
            for (int dt = 0; dt < 4; ++dt) {
                const uint16_t* vb = Vt + (size_t)(dt * 16 + li) * MCOL + c0 + kc * 32 + g * 8;
                short8 bv = ldb8(vb);
                ctx[dt] = __builtin_amdgcn_mfma_f32_16x16x32_bf16(pa, bv, ctx[dt], 0, 0, 0);
            }
        }
    }
    // write context partial for this strip
    float* cbase = ctx_out + (size_t)s * NROW * DH;
#pragma unroll
    for (int dt = 0; dt < 4; ++dt)
#pragma unroll
        for (int j = 0; j < 4; ++j)
            cbase[(size_t)(rw + g * 4 + j) * DH + dt * 16 + li] = ctx[dt][j];
}

// ---------------- k_red: reduce context strip partials ------------------------
__global__ __launch_bounds__(256) void k_red(const float* __restrict__ cpart,
                                             float* __restrict__ out, int nstrip) {
    int i = blockIdx.x * 256 + threadIdx.x;   // 524288 total
    float a = 0.f;
    for (int s = 0; s < nstrip; ++s) a += cpart[(size_t)s * (NROW * DH) + i];
    out[i] = a;
}

extern "C" void kernel_launch(void* const* d_in, const int* in_sizes, int n_in,
                              void* d_out, int out_size, void* d_ws, size_t ws_size,
                              hipStream_t stream) {
    const float* Q = (const float*)d_in[0];
    const float* K = (const float*)d_in[1];
    const float* V = (const float*)d_in[2];
    const int* mask = (const int*)d_in[3];

    float* out_ctx = (float*)d_out;
    float* out_prob = out_ctx + (size_t)NROW * DH;
    char* ws = (char*)d_ws;

    uint16_t* Qb = (uint16_t*)(ws);
    uint16_t* Kb = (uint16_t*)(ws + (1u << 20));
    uint16_t* Vt = (uint16_t*)(ws + (2u << 20));
    float* lpart = (float*)(ws + (3u << 20));
    size_t off_pm = (3u << 20) + (1u << 19);               // 3.5 MB
    unsigned long long* pm2 = (unsigned long long*)(ws + off_pm);
    size_t pm_bytes = (size_t)128 * NROW * 8;              // 8 MB
    size_t ctx_bytes8 = (size_t)8 * NROW * DH * 4;         // 16 MB
    size_t need_full = off_pm + pm_bytes + ctx_bytes8;
    size_t need_nopm = off_pm + ctx_bytes8;

    int nstrip; bool packed; float* ctx_out;
    if (ws_size >= need_full)      { packed = true;  nstrip = 8; ctx_out = (float*)(ws + off_pm + pm_bytes); }
    else if (ws_size >= need_nopm) { packed = false; nstrip = 8; ctx_out = (float*)(ws + off_pm); }
    else                           { packed = false; nstrip = 1; ctx_out = out_ctx; }

    k_prep<<<dim3(1152), dim3(256), 0, stream>>>(Q, K, V, Qb, Kb, Vt);
    k_pass1<<<dim3(128, nstrip), dim3(256), 0, stream>>>(Qb, Kb, mask, pm2, lpart,
                                                         nstrip, packed ? 1 : 0);
    if (packed)
        k_pass2<true><<<dim3(128, nstrip), dim3(256), 0, stream>>>(
            Qb, Kb, Vt, mask, pm2, lpart, out_prob, ctx_out, nstrip);
    else
        k_pass2<false><<<dim3(128, nstrip), dim3(256), 0, stream>>>(
            Qb, Kb, Vt, mask, pm2, lpart, out_prob, ctx_out, nstrip);
    if (nstrip > 1)
        k_red<<<dim3(2048), dim3(256), 0, stream>>>(ctx_out, out_ctx, nstrip);
}

// Round 4
// 353.610 us; speedup vs baseline: 1.0054x; 1.0054x over previous
//
#include <hip/hip_runtime.h>
#include <stdint.h>

#define NROW 8192
#define MCOL 8192
#define DH 64

// scale * log2(e): softmax computed as exp2(s * SC2) / sum
#define SC2 0.18033688011112042f

typedef __attribute__((ext_vector_type(8))) short short8;   // 8 bf16 (4 VGPRs)
typedef __attribute__((ext_vector_type(4))) short bf16x4;   // 4 bf16 (2 VGPRs)
typedef __attribute__((ext_vector_type(4))) float f32x4;

__device__ __forceinline__ short8 ldb8(const uint16_t* p) {
    return *reinterpret_cast<const short8*>(p);
}

__device__ __forceinline__ uint16_t f2bf(float f) {
    uint32_t u = __builtin_bit_cast(uint32_t, f);
    uint32_t r = (u + 0x7fffu + ((u >> 16) & 1u)) >> 16;
    return (uint16_t)r;
}

__device__ __forceinline__ float bf2f(uint16_t u) {
    return __builtin_bit_cast(float, (uint32_t)u << 16);
}

// ---------------- k_prep: Q,K -> bf16 ; V -> bf16 transposed Vt[d][c] ---------
__global__ __launch_bounds__(256) void k_prep(const float* __restrict__ Q,
                                              const float* __restrict__ K,
                                              const float* __restrict__ V,
                                              uint16_t* __restrict__ Qb,
                                              uint16_t* __restrict__ Kb,
                                              uint16_t* __restrict__ Vt) {
    int b = blockIdx.x, t = threadIdx.x;
    if (b < 128) {
        // transpose V rows [c0, c0+64) into Vt[dv][c]
        __shared__ float tile[64][65];
        int c0 = b * 64;
#pragma unroll
        for (int it = 0; it < 4; ++it) {
            int r = it * 16 + (t >> 4);
            int col = (t & 15) * 4;
            f32x4 v = *reinterpret_cast<const f32x4*>(V + (size_t)(c0 + r) * DH + col);
            tile[r][col + 0] = v[0]; tile[r][col + 1] = v[1];
            tile[r][col + 2] = v[2]; tile[r][col + 3] = v[3];
        }
        __syncthreads();
        int dv = t >> 2, cs = (t & 3) * 16;
        short8 o0, o1;
#pragma unroll
        for (int i = 0; i < 8; ++i) o0[i] = (short)f2bf(tile[cs + i][dv]);
#pragma unroll
        for (int i = 0; i < 8; ++i) o1[i] = (short)f2bf(tile[cs + 8 + i][dv]);
        *reinterpret_cast<short8*>(Vt + (size_t)dv * MCOL + c0 + cs) = o0;
        *reinterpret_cast<short8*>(Vt + (size_t)dv * MCOL + c0 + cs + 8) = o1;
    } else {
        const float* src; uint16_t* dst; int base;
        if (b < 640) { base = (b - 128) * 1024 + t * 4; src = Q; dst = Qb; }
        else         { base = (b - 640) * 1024 + t * 4; src = K; dst = Kb; }
        f32x4 v = *reinterpret_cast<const f32x4*>(src + base);
        uint64_t pk = (uint64_t)f2bf(v[0]) | ((uint64_t)f2bf(v[1]) << 16) |
                      ((uint64_t)f2bf(v[2]) << 32) | ((uint64_t)f2bf(v[3]) << 48);
        *reinterpret_cast<uint64_t*>(dst + base) = pk;
    }
}

// ---------------- k_pass1: row sums of masked exp + mask bit-packing ----------
__global__ __launch_bounds__(256) void k_pass1(const uint16_t* __restrict__ Qb,
                                               const uint16_t* __restrict__ Kb,
                                               const int* __restrict__ mask,
                                               unsigned long long* __restrict__ pm2,
                                               float* __restrict__ lpart,
                                               int nstrip, int write_pm) {
    int rb = blockIdx.x, s = blockIdx.y;
    int t = threadIdx.x, lane = t & 63, w = t >> 6;
    int rw = rb * 64 + w * 16;
    int li = lane & 15, g = lane >> 4;

    const uint16_t* qbase = Qb + (size_t)(rw + li) * DH + g * 8;
    short8 qa0 = ldb8(qbase), qa1 = ldb8(qbase + 32);

    float rs[4] = {0.f, 0.f, 0.f, 0.f};
    int steps = 128 / nstrip;

    for (int ccl = 0; ccl < steps; ++ccl) {
        int cc = s * steps + ccl;
        int c0 = cc * 64;
        // pack 16 rows x 64 cols of mask into one u64 per row (bit i = col c0+i)
        unsigned long long myw = 0ull;
#pragma unroll
        for (int rr = 0; rr < 16; ++rr) {
            int v = mask[(size_t)(rw + rr) * MCOL + c0 + lane];
            unsigned long long bl = __ballot(v != 0);
            if (lane == rr) myw = bl;
        }
        if (write_pm && lane < 16)
            pm2[(size_t)cc * NROW + rw + lane] = myw;
        unsigned long long w64[4];
#pragma unroll
        for (int j = 0; j < 4; ++j) w64[j] = __shfl(myw, g * 4 + j);

#pragma unroll
        for (int ct = 0; ct < 4; ++ct) {
            const uint16_t* kbase = Kb + (size_t)(c0 + ct * 16 + li) * DH + g * 8;
            short8 kb0 = ldb8(kbase), kb1 = ldb8(kbase + 32);
            f32x4 acc = {0.f, 0.f, 0.f, 0.f};
            acc = __builtin_amdgcn_mfma_f32_16x16x32_bf16(qa0, kb0, acc, 0, 0, 0);
            acc = __builtin_amdgcn_mfma_f32_16x16x32_bf16(qa1, kb1, acc, 0, 0, 0);
            int bi = ct * 16 + li;
#pragma unroll
            for (int j = 0; j < 4; ++j) {
                if (!((w64[j] >> bi) & 1ull))
                    rs[j] += __builtin_amdgcn_exp2f(acc[j] * SC2);
            }
        }
    }
    // reduce across the 16 lanes of each group (cols), write per-strip partials
#pragma unroll
    for (int j = 0; j < 4; ++j) {
        rs[j] += __shfl_xor(rs[j], 1);
        rs[j] += __shfl_xor(rs[j], 2);
        rs[j] += __shfl_xor(rs[j], 4);
        rs[j] += __shfl_xor(rs[j], 8);
    }
    if (li == 0) {
        f32x4 o = {rs[0], rs[1], rs[2], rs[3]};
        *reinterpret_cast<f32x4*>(lpart + (size_t)s * NROW + rw + g * 4) = o;
    }
}

// ---------------- k_pass2: probs + context partials ---------------------------
template <bool PACKED>
__global__ __launch_bounds__(256, 8) void k_pass2(const uint16_t* __restrict__ Qb,
                                               const uint16_t* __restrict__ Kb,
                                               const uint16_t* __restrict__ Vt,
                                               const int* __restrict__ mask,
                                               const unsigned long long* __restrict__ pm2,
                                               const float* __restrict__ lpart,
                                               float* __restrict__ out_prob,
                                               float* __restrict__ ctx_out,
                                               int nstrip) {
    __shared__ uint16_t pt[4][1024];   // per-wave 16x64 bf16, XOR-swizzled
    int rb = blockIdx.x, s = blockIdx.y;
    int t = threadIdx.x, lane = t & 63, w = t >> 6;
    int rw = rb * 64 + w * 16;
    int li = lane & 15, g = lane >> 4;

    // 1/l for this group's 4 rows (sum strip partials)
    f32x4 lsum = {0.f, 0.f, 0.f, 0.f};
    for (int s2 = 0; s2 < nstrip; ++s2)
        lsum += *reinterpret_cast<const f32x4*>(lpart + (size_t)s2 * NROW + rw + g * 4);
    float rinv[4];
#pragma unroll
    for (int j = 0; j < 4; ++j) rinv[j] = 1.0f / lsum[j];

    const uint16_t* qbase = Qb + (size_t)(rw + li) * DH + g * 8;
    short8 qa0 = ldb8(qbase), qa1 = ldb8(qbase + 32);

    f32x4 ctx[4];
#pragma unroll
    for (int dt = 0; dt < 4; ++dt) ctx[dt] = (f32x4){0.f, 0.f, 0.f, 0.f};

    int steps = 128 / nstrip;
    for (int ccl = 0; ccl < steps; ++ccl) {
        int cc = s * steps + ccl;
        int c0 = cc * 64;
        unsigned long long w64[4];
        if (PACKED) {
            const unsigned long long* pmr = pm2 + (size_t)cc * NROW + rw;
#pragma unroll
            for (int j = 0; j < 4; ++j) w64[j] = pmr[g * 4 + j];
        }
#pragma unroll
        for (int ct = 0; ct < 4; ++ct) {
            const uint16_t* kbase = Kb + (size_t)(c0 + ct * 16 + li) * DH + g * 8;
            short8 kb0 = ldb8(kbase), kb1 = ldb8(kbase + 32);
            f32x4 acc = {0.f, 0.f, 0.f, 0.f};
            acc = __builtin_amdgcn_mfma_f32_16x16x32_bf16(qa0, kb0, acc, 0, 0, 0);
            acc = __builtin_amdgcn_mfma_f32_16x16x32_bf16(qa1, kb1, acc, 0, 0, 0);
            int bi = ct * 16 + li;
#pragma unroll
            for (int j = 0; j < 4; ++j) {
                int m = g * 4 + j;
                int bit;
                if (PACKED) bit = (int)((w64[j] >> bi) & 1ull);
                else        bit = (mask[(size_t)(rw + m) * MCOL + c0 + bi] != 0);
                float p = bit ? 0.0f : __builtin_amdgcn_exp2f(acc[j] * SC2) * rinv[j];
                int e = ((m << 6) + bi) ^ ((m & 7) << 3);
                pt[w][e] = f2bf(p);
            }
        }
        // fence: keep the ds_writes above from being scheduled past the reads below
        __builtin_amdgcn_sched_barrier(0);
        // prob store: read bf16 tile back (short-family = legal aliasing with
        // uint16_t), convert, fully-coalesced float4 stores (1 KB/wave-instr)
#pragma unroll
        for (int it = 0; it < 4; ++it) {
            int m = it * 4 + g;          // row 0..15
            int cb = li * 4;             // col base, multiple of 4
            int e = (m << 6) + (cb ^ ((m & 7) << 3));
            bf16x4 raw = *reinterpret_cast<const bf16x4*>(&pt[w][e]);
            f32x4 o;
            o[0] = bf2f((uint16_t)raw[0]);
            o[1] = bf2f((uint16_t)raw[1]);
            o[2] = bf2f((uint16_t)raw[2]);
            o[3] = bf2f((uint16_t)raw[3]);
            *reinterpret_cast<f32x4*>(&out_prob[(size_t)(rw + m) * MCOL + c0 + cb]) = o;
        }
        // PV: context += P(16x64) * V(64x64) via transposed-LDS A-fragments
#pragma unroll
        for (int kc = 0; kc < 2; ++kc) {
            int eidx = ((li << 6) + kc * 32 + (g << 3)) ^ ((li & 7) << 3);
            short8 pa = *reinterpret_cast<const short8*>(&pt[w][eidx]);
#pragma unroll
            for (int dt = 0; dt < 4; ++dt) {
                const uint16_t* vb = Vt + (size_t)(dt * 16 + li) * MCOL + c0 + kc * 32 + g * 8;
                short8 bv = ldb8(vb);
                ctx[dt] = __builtin_amdgcn_mfma_f32_16x16x32_bf16(pa, bv, ctx[dt], 0, 0, 0);
            }
        }
        __builtin_amdgcn_sched_barrier(0);
    }
    // write context partial for this strip
    float* cbase = ctx_out + (size_t)s * NROW * DH;
#pragma unroll
    for (int dt = 0; dt < 4; ++dt)
#pragma unroll
        for (int j = 0; j < 4; ++j)
            cbase[(size_t)(rw + g * 4 + j) * DH + dt * 16 + li] = ctx[dt][j];
}

// ---------------- k_red: reduce context strip partials ------------------------
__global__ __launch_bounds__(256) void k_red(const float* __restrict__ cpart,
                                             float* __restrict__ out, int nstrip) {
    int i = blockIdx.x * 256 + threadIdx.x;   // 524288 total
    float a = 0.f;
    for (int s = 0; s < nstrip; ++s) a += cpart[(size_t)s * (NROW * DH) + i];
    out[i] = a;
}

extern "C" void kernel_launch(void* const* d_in, const int* in_sizes, int n_in,
                              void* d_out, int out_size, void* d_ws, size_t ws_size,
                              hipStream_t stream) {
    const float* Q = (const float*)d_in[0];
    const float* K = (const float*)d_in[1];
    const float* V = (const float*)d_in[2];
    const int* mask = (const int*)d_in[3];

    float* out_ctx = (float*)d_out;
    float* out_prob = out_ctx + (size_t)NROW * DH;
    char* ws = (char*)d_ws;

    uint16_t* Qb = (uint16_t*)(ws);
    uint16_t* Kb = (uint16_t*)(ws + (1u << 20));
    uint16_t* Vt = (uint16_t*)(ws + (2u << 20));
    float* lpart = (float*)(ws + (3u << 20));          // up to 16 strips x 32 KB
    size_t off_pm = (3u << 20) + (1u << 19);           // 3.5 MB
    unsigned long long* pm2 = (unsigned long long*)(ws + off_pm);
    size_t pm_bytes = (size_t)128 * NROW * 8;          // 8 MB
    size_t off_ctx = off_pm + pm_bytes;                // 11.5 MB
    size_t ctx_strip = (size_t)NROW * DH * 4;          // 2 MB per strip

    int nstrip; bool packed; float* ctx_out;
    if (ws_size >= off_ctx + 16 * ctx_strip)      { packed = true;  nstrip = 16; ctx_out = (float*)(ws + off_ctx); }
    else if (ws_size >= off_ctx + 8 * ctx_strip)  { packed = true;  nstrip = 8;  ctx_out = (float*)(ws + off_ctx); }
    else if (ws_size >= off_pm + 8 * ctx_strip)   { packed = false; nstrip = 8;  ctx_out = (float*)(ws + off_pm); }
    else                                          { packed = false; nstrip = 1;  ctx_out = out_ctx; }

    k_prep<<<dim3(1152), dim3(256), 0, stream>>>(Q, K, V, Qb, Kb, Vt);
    k_pass1<<<dim3(128, nstrip), dim3(256), 0, stream>>>(Qb, Kb, mask, pm2, lpart,
                                                         nstrip, packed ? 1 : 0);
    if (packed)
        k_pass2<true><<<dim3(128, nstrip), dim3(256), 0, stream>>>(
            Qb, Kb, Vt, mask, pm2, lpart, out_prob, ctx_out, nstrip);
    else
        k_pass2<false><<<dim3(128, nstrip), dim3(256), 0, stream>>>(
            Qb, Kb, Vt, mask, pm2, lpart, out_prob, ctx_out, nstrip);
    if (nstrip > 1)
        k_red<<<dim3(2048), dim3(256), 0, stream>>>(ctx_out, out_ctx, nstrip);
}

// Round 5
// 319.312 us; speedup vs baseline: 1.1133x; 1.1074x over previous
//
#include <hip/hip_runtime.h>
#include <stdint.h>

#define NROW 8192
#define MCOL 8192
#define DH 64

// scale * log2(e): softmax computed as exp2(s * SC2) / sum
#define SC2 0.18033688011112042f

typedef __attribute__((ext_vector_type(8))) short short8;   // 8 bf16 (4 VGPRs)
typedef __attribute__((ext_vector_type(4))) short bf16x4;   // 4 bf16 (2 VGPRs)
typedef __attribute__((ext_vector_type(4))) float f32x4;

__device__ __forceinline__ short8 ldb8(const uint16_t* p) {
    return *reinterpret_cast<const short8*>(p);
}

__device__ __forceinline__ uint16_t f2bf(float f) {
    uint32_t u = __builtin_bit_cast(uint32_t, f);
    uint32_t r = (u + 0x7fffu + ((u >> 16) & 1u)) >> 16;
    return (uint16_t)r;
}

__device__ __forceinline__ float bf2f(uint16_t u) {
    return __builtin_bit_cast(float, (uint32_t)u << 16);
}

// ---------------- k_prep: Q,K -> bf16 ; V -> bf16 transposed Vt[d][c] ---------
__global__ __launch_bounds__(256) void k_prep(const float* __restrict__ Q,
                                              const float* __restrict__ K,
                                              const float* __restrict__ V,
                                              uint16_t* __restrict__ Qb,
                                              uint16_t* __restrict__ Kb,
                                              uint16_t* __restrict__ Vt) {
    int b = blockIdx.x, t = threadIdx.x;
    if (b < 128) {
        // transpose V rows [c0, c0+64) into Vt[dv][c]
        __shared__ float tile[64][65];
        int c0 = b * 64;
#pragma unroll
        for (int it = 0; it < 4; ++it) {
            int r = it * 16 + (t >> 4);
            int col = (t & 15) * 4;
            f32x4 v = *reinterpret_cast<const f32x4*>(V + (size_t)(c0 + r) * DH + col);
            tile[r][col + 0] = v[0]; tile[r][col + 1] = v[1];
            tile[r][col + 2] = v[2]; tile[r][col + 3] = v[3];
        }
        __syncthreads();
        int dv = t >> 2, cs = (t & 3) * 16;
        short8 o0, o1;
#pragma unroll
        for (int i = 0; i < 8; ++i) o0[i] = (short)f2bf(tile[cs + i][dv]);
#pragma unroll
        for (int i = 0; i < 8; ++i) o1[i] = (short)f2bf(tile[cs + 8 + i][dv]);
        *reinterpret_cast<short8*>(Vt + (size_t)dv * MCOL + c0 + cs) = o0;
        *reinterpret_cast<short8*>(Vt + (size_t)dv * MCOL + c0 + cs + 8) = o1;
    } else {
        const float* src; uint16_t* dst; int base;
        if (b < 640) { base = (b - 128) * 1024 + t * 4; src = Q; dst = Qb; }
        else         { base = (b - 640) * 1024 + t * 4; src = K; dst = Kb; }
        f32x4 v = *reinterpret_cast<const f32x4*>(src + base);
        uint64_t pk = (uint64_t)f2bf(v[0]) | ((uint64_t)f2bf(v[1]) << 16) |
                      ((uint64_t)f2bf(v[2]) << 32) | ((uint64_t)f2bf(v[3]) << 48);
        *reinterpret_cast<uint64_t*>(dst + base) = pk;
    }
}

// ---------------- k_pass1: row sums of masked exp + mask bit-packing ----------
__global__ __launch_bounds__(256) void k_pass1(const uint16_t* __restrict__ Qb,
                                               const uint16_t* __restrict__ Kb,
                                               const int* __restrict__ mask,
                                               unsigned long long* __restrict__ pm2,
                                               float* __restrict__ lpart,
                                               int nstrip, int write_pm) {
    int rb = blockIdx.x, s = blockIdx.y;
    int t = threadIdx.x, lane = t & 63, w = t >> 6;
    int rw = rb * 64 + w * 16;
    int li = lane & 15, g = lane >> 4;

    const uint16_t* qbase = Qb + (size_t)(rw + li) * DH + g * 8;
    short8 qa0 = ldb8(qbase), qa1 = ldb8(qbase + 32);

    float rs[4] = {0.f, 0.f, 0.f, 0.f};
    int steps = 128 / nstrip;

    for (int ccl = 0; ccl < steps; ++ccl) {
        int cc = s * steps + ccl;
        int c0 = cc * 64;
        // pack 16 rows x 64 cols of mask into one u64 per row (bit i = col c0+i)
        // NT loads: mask is stream-once, keep it out of L2
        unsigned long long myw = 0ull;
#pragma unroll
        for (int rr = 0; rr < 16; ++rr) {
            int v = __builtin_nontemporal_load(&mask[(size_t)(rw + rr) * MCOL + c0 + lane]);
            unsigned long long bl = __ballot(v != 0);
            if (lane == rr) myw = bl;
        }
        if (write_pm && lane < 16)
            pm2[(size_t)cc * NROW + rw + lane] = myw;
        unsigned long long w64[4];
#pragma unroll
        for (int j = 0; j < 4; ++j) w64[j] = __shfl(myw, g * 4 + j);

#pragma unroll
        for (int ct = 0; ct < 4; ++ct) {
            const uint16_t* kbase = Kb + (size_t)(c0 + ct * 16 + li) * DH + g * 8;
            short8 kb0 = ldb8(kbase), kb1 = ldb8(kbase + 32);
            f32x4 acc = {0.f, 0.f, 0.f, 0.f};
            acc = __builtin_amdgcn_mfma_f32_16x16x32_bf16(qa0, kb0, acc, 0, 0, 0);
            acc = __builtin_amdgcn_mfma_f32_16x16x32_bf16(qa1, kb1, acc, 0, 0, 0);
            int bi = ct * 16 + li;
#pragma unroll
            for (int j = 0; j < 4; ++j) {
                if (!((w64[j] >> bi) & 1ull))
                    rs[j] += __builtin_amdgcn_exp2f(acc[j] * SC2);
            }
        }
    }
    // reduce across the 16 lanes of each group (cols), write per-strip partials
#pragma unroll
    for (int j = 0; j < 4; ++j) {
        rs[j] += __shfl_xor(rs[j], 1);
        rs[j] += __shfl_xor(rs[j], 2);
        rs[j] += __shfl_xor(rs[j], 4);
        rs[j] += __shfl_xor(rs[j], 8);
    }
    if (li == 0) {
        f32x4 o = {rs[0], rs[1], rs[2], rs[3]};
        *reinterpret_cast<f32x4*>(lpart + (size_t)s * NROW + rw + g * 4) = o;
    }
}

// ---------------- k_pass2: probs + context partials ---------------------------
template <bool PACKED>
__global__ __launch_bounds__(256, 8) void k_pass2(const uint16_t* __restrict__ Qb,
                                               const uint16_t* __restrict__ Kb,
                                               const uint16_t* __restrict__ Vt,
                                               const int* __restrict__ mask,
                                               const unsigned long long* __restrict__ pm2,
                                               const float* __restrict__ lpart,
                                               float* __restrict__ out_prob,
                                               float* __restrict__ ctx_out,
                                               int nstrip) {
    __shared__ uint16_t pt[4][1024];   // per-wave 16x64 bf16, XOR-swizzled
    int rb = blockIdx.x, s = blockIdx.y;
    int t = threadIdx.x, lane = t & 63, w = t >> 6;
    int rw = rb * 64 + w * 16;
    int li = lane & 15, g = lane >> 4;

    // 1/l for this group's 4 rows (sum strip partials)
    f32x4 lsum = {0.f, 0.f, 0.f, 0.f};
    for (int s2 = 0; s2 < nstrip; ++s2)
        lsum += *reinterpret_cast<const f32x4*>(lpart + (size_t)s2 * NROW + rw + g * 4);
    float rinv[4];
#pragma unroll
    for (int j = 0; j < 4; ++j) rinv[j] = 1.0f / lsum[j];

    const uint16_t* qbase = Qb + (size_t)(rw + li) * DH + g * 8;
    short8 qa0 = ldb8(qbase), qa1 = ldb8(qbase + 32);

    f32x4 ctx[4];
#pragma unroll
    for (int dt = 0; dt < 4; ++dt) ctx[dt] = (f32x4){0.f, 0.f, 0.f, 0.f};

    int steps = 128 / nstrip;
    for (int ccl = 0; ccl < steps; ++ccl) {
        int cc = s * steps + ccl;
        int c0 = cc * 64;
        unsigned long long w64[4];
        if (PACKED) {
            const unsigned long long* pmr = pm2 + (size_t)cc * NROW + rw;
#pragma unroll
            for (int j = 0; j < 4; ++j) w64[j] = pmr[g * 4 + j];
        }
#pragma unroll
        for (int ct = 0; ct < 4; ++ct) {
            const uint16_t* kbase = Kb + (size_t)(c0 + ct * 16 + li) * DH + g * 8;
            short8 kb0 = ldb8(kbase), kb1 = ldb8(kbase + 32);
            f32x4 acc = {0.f, 0.f, 0.f, 0.f};
            acc = __builtin_amdgcn_mfma_f32_16x16x32_bf16(qa0, kb0, acc, 0, 0, 0);
            acc = __builtin_amdgcn_mfma_f32_16x16x32_bf16(qa1, kb1, acc, 0, 0, 0);
            int bi = ct * 16 + li;
#pragma unroll
            for (int j = 0; j < 4; ++j) {
                int m = g * 4 + j;
                int bit;
                if (PACKED) bit = (int)((w64[j] >> bi) & 1ull);
                else        bit = (mask[(size_t)(rw + m) * MCOL + c0 + bi] != 0);
                float p = bit ? 0.0f : __builtin_amdgcn_exp2f(acc[j] * SC2) * rinv[j];
                int e = ((m << 6) + bi) ^ ((m & 7) << 3);
                pt[w][e] = f2bf(p);
            }
        }
        // prob store: read bf16 tile back (short-family aliasing with the
        // uint16_t ds_writes above -> compiler-visible dependency, no fence
        // needed), convert, coalesced NON-TEMPORAL float4 stores so the
        // 268 MB prob stream doesn't evict K/V from L2.
#pragma unroll
        for (int it = 0; it < 4; ++it) {
            int m = it * 4 + g;          // row 0..15
            int cb = li * 4;             // col base, multiple of 4
            int e = (m << 6) + (cb ^ ((m & 7) << 3));
            bf16x4 raw = *reinterpret_cast<const bf16x4*>(&pt[w][e]);
            f32x4 o;
            o[0] = bf2f((uint16_t)raw[0]);
            o[1] = bf2f((uint16_t)raw[1]);
            o[2] = bf2f((uint16_t)raw[2]);
            o[3] = bf2f((uint16_t)raw[3]);
            __builtin_nontemporal_store(
                o, reinterpret_cast<f32x4*>(&out_prob[(size_t)(rw + m) * MCOL + c0 + cb]));
        }
        // PV: context += P(16x64) * V(64x64) via transposed-LDS A-fragments
#pragma unroll
        for (int kc = 0; kc < 2; ++kc) {
            int eidx = ((li << 6) + kc * 32 + (g << 3)) ^ ((li & 7) << 3);
            short8 pa = *reinterpret_cast<const short8*>(&pt[w][eidx]);
#pragma unroll
            for (int dt = 0; dt < 4; ++dt) {
                const uint16_t* vb = Vt + (size_t)(dt * 16 + li) * MCOL + c0 + kc * 32 + g * 8;
                short8 bv = ldb8(vb);
                ctx[dt] = __builtin_amdgcn_mfma_f32_16x16x32_bf16(pa, bv, ctx[dt], 0, 0, 0);
            }
        }
    }
    // write context partial for this strip (stream-once -> NT)
    float* cbase = ctx_out + (size_t)s * NROW * DH;
#pragma unroll
    for (int dt = 0; dt < 4; ++dt)
#pragma unroll
        for (int j = 0; j < 4; ++j)
            __builtin_nontemporal_store(
                ctx[dt][j], &cbase[(size_t)(rw + g * 4 + j) * DH + dt * 16 + li]);
}

// ---------------- k_red: reduce context strip partials ------------------------
__global__ __launch_bounds__(256) void k_red(const float* __restrict__ cpart,
                                             float* __restrict__ out, int nstrip) {
    int i = blockIdx.x * 256 + threadIdx.x;   // 524288 total
    float a = 0.f;
    for (int s = 0; s < nstrip; ++s)
        a += __builtin_nontemporal_load(&cpart[(size_t)s * (NROW * DH) + i]);
    out[i] = a;
}

extern "C" void kernel_launch(void* const* d_in, const int* in_sizes, int n_in,
                              void* d_out, int out_size, void* d_ws, size_t ws_size,
                              hipStream_t stream) {
    const float* Q = (const float*)d_in[0];
    const float* K = (const float*)d_in[1];
    const float* V = (const float*)d_in[2];
    const int* mask = (const int*)d_in[3];

    float* out_ctx = (float*)d_out;
    float* out_prob = out_ctx + (size_t)NROW * DH;
    char* ws = (char*)d_ws;

    uint16_t* Qb = (uint16_t*)(ws);
    uint16_t* Kb = (uint16_t*)(ws + (1u << 20));
    uint16_t* Vt = (uint16_t*)(ws + (2u << 20));
    float* lpart = (float*)(ws + (3u << 20));          // up to 16 strips x 32 KB
    size_t off_pm = (3u << 20) + (1u << 19);           // 3.5 MB
    unsigned long long* pm2 = (unsigned long long*)(ws + off_pm);
    size_t pm_bytes = (size_t)128 * NROW * 8;          // 8 MB
    size_t off_ctx = off_pm + pm_bytes;                // 11.5 MB
    size_t ctx_strip = (size_t)NROW * DH * 4;          // 2 MB per strip

    int nstrip; bool packed; float* ctx_out;
    if (ws_size >= off_ctx + 16 * ctx_strip)      { packed = true;  nstrip = 16; ctx_out = (float*)(ws + off_ctx); }
    else if (ws_size >= off_ctx + 8 * ctx_strip)  { packed = true;  nstrip = 8;  ctx_out = (float*)(ws + off_ctx); }
    else if (ws_size >= off_pm + 8 * ctx_strip)   { packed = false; nstrip = 8;  ctx_out = (float*)(ws + off_pm); }
    else                                          { packed = false; nstrip = 1;  ctx_out = out_ctx; }

    k_prep<<<dim3(1152), dim3(256), 0, stream>>>(Q, K, V, Qb, Kb, Vt);
    k_pass1<<<dim3(128, nstrip), dim3(256), 0, stream>>>(Qb, Kb, mask, pm2, lpart,
                                                         nstrip, packed ? 1 : 0);
    if (packed)
        k_pass2<true><<<dim3(128, nstrip), dim3(256), 0, stream>>>(
            Qb, Kb, Vt, mask, pm2, lpart, out_prob, ctx_out, nstrip);
    else
        k_pass2<false><<<dim3(128, nstrip), dim3(256), 0, stream>>>(
            Qb, Kb, Vt, mask, pm2, lpart, out_prob, ctx_out, nstrip);
    if (nstrip > 1)
        k_red<<<dim3(2048), dim3(256), 0, stream>>>(ctx_out, out_ctx, nstrip);
}

// Round 6
// 316.286 us; speedup vs baseline: 1.1240x; 1.0096x over previous
//
#include <hip/hip_runtime.h>
#include <stdint.h>

#define NROW 8192
#define MCOL 8192
#define DH 64

// scale * log2(e): softmax computed as exp2(s * SC2) / sum
#define SC2 0.18033688011112042f

typedef __attribute__((ext_vector_type(8))) short short8;   // 8 bf16 (4 VGPRs)
typedef __attribute__((ext_vector_type(4))) short bf16x4;   // 4 bf16 (2 VGPRs)
typedef __attribute__((ext_vector_type(4))) float f32x4;

__device__ __forceinline__ short8 ldb8(const uint16_t* p) {
    return *reinterpret_cast<const short8*>(p);
}

__device__ __forceinline__ uint16_t f2bf(float f) {
    uint32_t u = __builtin_bit_cast(uint32_t, f);
    uint32_t r = (u + 0x7fffu + ((u >> 16) & 1u)) >> 16;
    return (uint16_t)r;
}

__device__ __forceinline__ float bf2f(uint16_t u) {
    return __builtin_bit_cast(float, (uint32_t)u << 16);
}

// ---------------- k_prep: Q,K -> bf16 ; V -> bf16 transposed Vt[d][c] ---------
__global__ __launch_bounds__(256) void k_prep(const float* __restrict__ Q,
                                              const float* __restrict__ K,
                                              const float* __restrict__ V,
                                              uint16_t* __restrict__ Qb,
                                              uint16_t* __restrict__ Kb,
                                              uint16_t* __restrict__ Vt) {
    int b = blockIdx.x, t = threadIdx.x;
    if (b < 128) {
        // transpose V rows [c0, c0+64) into Vt[dv][c]
        __shared__ float tile[64][65];
        int c0 = b * 64;
#pragma unroll
        for (int it = 0; it < 4; ++it) {
            int r = it * 16 + (t >> 4);
            int col = (t & 15) * 4;
            f32x4 v = *reinterpret_cast<const f32x4*>(V + (size_t)(c0 + r) * DH + col);
            tile[r][col + 0] = v[0]; tile[r][col + 1] = v[1];
            tile[r][col + 2] = v[2]; tile[r][col + 3] = v[3];
        }
        __syncthreads();
        int dv = t >> 2, cs = (t & 3) * 16;
        short8 o0, o1;
#pragma unroll
        for (int i = 0; i < 8; ++i) o0[i] = (short)f2bf(tile[cs + i][dv]);
#pragma unroll
        for (int i = 0; i < 8; ++i) o1[i] = (short)f2bf(tile[cs + 8 + i][dv]);
        *reinterpret_cast<short8*>(Vt + (size_t)dv * MCOL + c0 + cs) = o0;
        *reinterpret_cast<short8*>(Vt + (size_t)dv * MCOL + c0 + cs + 8) = o1;
    } else {
        const float* src; uint16_t* dst; int base;
        if (b < 640) { base = (b - 128) * 1024 + t * 4; src = Q; dst = Qb; }
        else         { base = (b - 640) * 1024 + t * 4; src = K; dst = Kb; }
        f32x4 v = *reinterpret_cast<const f32x4*>(src + base);
        uint64_t pk = (uint64_t)f2bf(v[0]) | ((uint64_t)f2bf(v[1]) << 16) |
                      ((uint64_t)f2bf(v[2]) << 32) | ((uint64_t)f2bf(v[3]) << 48);
        *reinterpret_cast<uint64_t*>(dst + base) = pk;
    }
}

// swizzled LDS chunk layout: element (row, u16col) lives at
//   u16 index row*64 + (u16col ^ ((row&7)<<3))          [byte ^= (row&7)<<4]
// stage: thread t (512 threads) writes 16B: row=t>>3, bytecol=(t&7)<<4.

// ---------------- k_pass1: row sums of masked exp + mask bit-packing ----------
__global__ __launch_bounds__(512, 8) void k_pass1(const uint16_t* __restrict__ Qb,
                                               const uint16_t* __restrict__ Kb,
                                               const int* __restrict__ mask,
                                               unsigned long long* __restrict__ pm2,
                                               float* __restrict__ lpart,
                                               int nstrip, int write_pm) {
    __shared__ uint16_t ks[4096];      // 64x64 bf16 K-chunk, XOR-swizzled
    int rb = blockIdx.x, s = blockIdx.y;
    int t = threadIdx.x, lane = t & 63, w = t >> 6;
    int rw = rb * 128 + w * 16;
    int li = lane & 15, g = lane >> 4;

    int srow = t >> 3;                           // 0..63
    int scol = ((t & 7) << 3) ^ ((srow & 7) << 3); // u16 col in global (pre-swizzled)

    const uint16_t* qbase = Qb + (size_t)(rw + li) * DH + g * 8;
    short8 qa0 = ldb8(qbase), qa1 = ldb8(qbase + 32);

    float rs[4] = {0.f, 0.f, 0.f, 0.f};
    int steps = 128 / nstrip;

    for (int ccl = 0; ccl < steps; ++ccl) {
        int cc = s * steps + ccl;
        int c0 = cc * 64;
        // stage K-chunk: 16B per thread, swizzled source -> linear LDS
        short8 kv = ldb8(Kb + (size_t)(c0 + srow) * DH + scol);
        __syncthreads();   // prior chunk fully consumed
        *reinterpret_cast<short8*>(&ks[t * 8]) = kv;

        // pack 16 rows x 64 cols of mask into one u64 per row (bit i = col c0+i)
        unsigned long long myw = 0ull;
#pragma unroll
        for (int rr = 0; rr < 16; ++rr) {
            int v = __builtin_nontemporal_load(&mask[(size_t)(rw + rr) * MCOL + c0 + lane]);
            unsigned long long bl = __ballot(v != 0);
            if (lane == rr) myw = bl;
        }
        if (write_pm && lane < 16)
            pm2[(size_t)cc * NROW + rw + lane] = myw;
        unsigned long long w64[4];
#pragma unroll
        for (int j = 0; j < 4; ++j) w64[j] = __shfl(myw, g * 4 + j);

        __syncthreads();   // K-chunk staged
#pragma unroll
        for (int ct = 0; ct < 4; ++ct) {
            int r = ct * 16 + li;
            short8 kb0 = ldb8(&ks[r * 64 + ((g * 8) ^ ((li & 7) << 3))]);
            short8 kb1 = ldb8(&ks[r * 64 + ((32 + g * 8) ^ ((li & 7) << 3))]);
            f32x4 acc = {0.f, 0.f, 0.f, 0.f};
            acc = __builtin_amdgcn_mfma_f32_16x16x32_bf16(qa0, kb0, acc, 0, 0, 0);
            acc = __builtin_amdgcn_mfma_f32_16x16x32_bf16(qa1, kb1, acc, 0, 0, 0);
            int bi = ct * 16 + li;
#pragma unroll
            for (int j = 0; j < 4; ++j) {
                if (!((w64[j] >> bi) & 1ull))
                    rs[j] += __builtin_amdgcn_exp2f(acc[j] * SC2);
            }
        }
    }
    // reduce across the 16 lanes of each group (cols), write per-strip partials
#pragma unroll
    for (int j = 0; j < 4; ++j) {
        rs[j] += __shfl_xor(rs[j], 1);
        rs[j] += __shfl_xor(rs[j], 2);
        rs[j] += __shfl_xor(rs[j], 4);
        rs[j] += __shfl_xor(rs[j], 8);
    }
    if (li == 0) {
        f32x4 o = {rs[0], rs[1], rs[2], rs[3]};
        *reinterpret_cast<f32x4*>(lpart + (size_t)s * NROW + rw + g * 4) = o;
    }
}

// ---------------- k_pass2: probs + context partials ---------------------------
__global__ __launch_bounds__(512, 8) void k_pass2(const uint16_t* __restrict__ Qb,
                                               const uint16_t* __restrict__ Kb,
                                               const uint16_t* __restrict__ Vt,
                                               const unsigned long long* __restrict__ pm2,
                                               const float* __restrict__ lpart,
                                               float* __restrict__ out_prob,
                                               float* __restrict__ ctx_out,
                                               int nstrip) {
    __shared__ uint16_t ks[4096];      // K-chunk, XOR-swizzled
    __shared__ uint16_t vs[4096];      // Vt-chunk [d][c], XOR-swizzled
    __shared__ uint16_t pt[8][1024];   // per-wave 16x64 bf16 P, XOR-swizzled
    int rb = blockIdx.x, s = blockIdx.y;
    int t = threadIdx.x, lane = t & 63, w = t >> 6;
    int rw = rb * 128 + w * 16;
    int li = lane & 15, g = lane >> 4;

    int srow = t >> 3;
    int scol = ((t & 7) << 3) ^ ((srow & 7) << 3);

    // 1/l for this group's 4 rows (sum strip partials)
    f32x4 lsum = {0.f, 0.f, 0.f, 0.f};
    for (int s2 = 0; s2 < nstrip; ++s2)
        lsum += *reinterpret_cast<const f32x4*>(lpart + (size_t)s2 * NROW + rw + g * 4);
    float rinv[4];
#pragma unroll
    for (int j = 0; j < 4; ++j) rinv[j] = 1.0f / lsum[j];

    const uint16_t* qbase = Qb + (size_t)(rw + li) * DH + g * 8;
    short8 qa0 = ldb8(qbase), qa1 = ldb8(qbase + 32);

    f32x4 ctx[4];
#pragma unroll
    for (int dt = 0; dt < 4; ++dt) ctx[dt] = (f32x4){0.f, 0.f, 0.f, 0.f};

    int steps = 128 / nstrip;
    for (int ccl = 0; ccl < steps; ++ccl) {
        int cc = s * steps + ccl;
        int c0 = cc * 64;
        // stage K and V chunks (16B each per thread)
        short8 kv = ldb8(Kb + (size_t)(c0 + srow) * DH + scol);
        short8 vv = ldb8(Vt + (size_t)srow * MCOL + c0 + scol);
        unsigned long long w64[4];
        const unsigned long long* pmr = pm2 + (size_t)cc * NROW + rw;
#pragma unroll
        for (int j = 0; j < 4; ++j) w64[j] = pmr[g * 4 + j];

        __syncthreads();   // prior chunk fully consumed
        *reinterpret_cast<short8*>(&ks[t * 8]) = kv;
        *reinterpret_cast<short8*>(&vs[t * 8]) = vv;
        __syncthreads();   // chunks staged

#pragma unroll
        for (int ct = 0; ct < 4; ++ct) {
            int r = ct * 16 + li;
            short8 kb0 = ldb8(&ks[r * 64 + ((g * 8) ^ ((li & 7) << 3))]);
            short8 kb1 = ldb8(&ks[r * 64 + ((32 + g * 8) ^ ((li & 7) << 3))]);
            f32x4 acc = {0.f, 0.f, 0.f, 0.f};
            acc = __builtin_amdgcn_mfma_f32_16x16x32_bf16(qa0, kb0, acc, 0, 0, 0);
            acc = __builtin_amdgcn_mfma_f32_16x16x32_bf16(qa1, kb1, acc, 0, 0, 0);
            int bi = ct * 16 + li;
#pragma unroll
            for (int j = 0; j < 4; ++j) {
                int m = g * 4 + j;
                int bit = (int)((w64[j] >> bi) & 1ull);
                float p = bit ? 0.0f : __builtin_amdgcn_exp2f(acc[j] * SC2) * rinv[j];
                int e = ((m << 6) + bi) ^ ((m & 7) << 3);
                pt[w][e] = f2bf(p);
            }
        }
        // prob store: read bf16 P-tile back, convert, coalesced NT float4 stores
#pragma unroll
        for (int it = 0; it < 4; ++it) {
            int m = it * 4 + g;          // row 0..15
            int cb = li * 4;             // col base, multiple of 4
            int e = (m << 6) + (cb ^ ((m & 7) << 3));
            bf16x4 raw = *reinterpret_cast<const bf16x4*>(&pt[w][e]);
            f32x4 o;
            o[0] = bf2f((uint16_t)raw[0]);
            o[1] = bf2f((uint16_t)raw[1]);
            o[2] = bf2f((uint16_t)raw[2]);
            o[3] = bf2f((uint16_t)raw[3]);
            __builtin_nontemporal_store(
                o, reinterpret_cast<f32x4*>(&out_prob[(size_t)(rw + m) * MCOL + c0 + cb]));
        }
        // PV: context += P(16x64) * V(64x64), both operands from LDS
#pragma unroll
        for (int kc = 0; kc < 2; ++kc) {
            int eidx = ((li << 6) + kc * 32 + (g << 3)) ^ ((li & 7) << 3);
            short8 pa = *reinterpret_cast<const short8*>(&pt[w][eidx]);
#pragma unroll
            for (int dt = 0; dt < 4; ++dt) {
                int d = dt * 16 + li;
                short8 bv = ldb8(&vs[d * 64 + ((kc * 32 + g * 8) ^ ((li & 7) << 3))]);
                ctx[dt] = __builtin_amdgcn_mfma_f32_16x16x32_bf16(pa, bv, ctx[dt], 0, 0, 0);
            }
        }
    }
    // write context partial for this strip (stream-once -> NT)
    float* cbase = ctx_out + (size_t)s * NROW * DH;
#pragma unroll
    for (int dt = 0; dt < 4; ++dt)
#pragma unroll
        for (int j = 0; j < 4; ++j)
            __builtin_nontemporal_store(
                ctx[dt][j], &cbase[(size_t)(rw + g * 4 + j) * DH + dt * 16 + li]);
}

// ---------------- k_red: reduce context strip partials ------------------------
__global__ __launch_bounds__(256) void k_red(const float* __restrict__ cpart,
                                             float* __restrict__ out, int nstrip) {
    int i = blockIdx.x * 256 + threadIdx.x;   // 524288 total
    float a = 0.f;
    for (int s = 0; s < nstrip; ++s)
        a += __builtin_nontemporal_load(&cpart[(size_t)s * (NROW * DH) + i]);
    out[i] = a;
}

extern "C" void kernel_launch(void* const* d_in, const int* in_sizes, int n_in,
                              void* d_out, int out_size, void* d_ws, size_t ws_size,
                              hipStream_t stream) {
    const float* Q = (const float*)d_in[0];
    const float* K = (const float*)d_in[1];
    const float* V = (const float*)d_in[2];
    const int* mask = (const int*)d_in[3];

    float* out_ctx = (float*)d_out;
    float* out_prob = out_ctx + (size_t)NROW * DH;
    char* ws = (char*)d_ws;

    uint16_t* Qb = (uint16_t*)(ws);
    uint16_t* Kb = (uint16_t*)(ws + (1u << 20));
    uint16_t* Vt = (uint16_t*)(ws + (2u << 20));
    float* lpart = (float*)(ws + (3u << 20));          // up to 16 strips x 32 KB
    size_t off_pm = (3u << 20) + (1u << 19);           // 3.5 MB
    unsigned long long* pm2 = (unsigned long long*)(ws + off_pm);
    size_t pm_bytes = (size_t)128 * NROW * 8;          // 8 MB
    size_t off_ctx = off_pm + pm_bytes;                // 11.5 MB
    size_t ctx_strip = (size_t)NROW * DH * 4;          // 2 MB per strip

    int nstrip; float* ctx_out;
    if (ws_size >= off_ctx + 16 * ctx_strip)      { nstrip = 16; ctx_out = (float*)(ws + off_ctx); }
    else if (ws_size >= off_ctx + 8 * ctx_strip)  { nstrip = 8;  ctx_out = (float*)(ws + off_ctx); }
    else                                          { nstrip = 1;  ctx_out = out_ctx; }

    k_prep<<<dim3(1152), dim3(256), 0, stream>>>(Q, K, V, Qb, Kb, Vt);
    k_pass1<<<dim3(64, nstrip), dim3(512), 0, stream>>>(Qb, Kb, mask, pm2, lpart,
                                                        nstrip, 1);
    k_pass2<<<dim3(64, nstrip), dim3(512), 0, stream>>>(
        Qb, Kb, Vt, pm2, lpart, out_prob, ctx_out, nstrip);
    if (nstrip > 1)
        k_red<<<dim3(2048), dim3(256), 0, stream>>>(ctx_out, out_ctx, nstrip);
}

// Round 7
// 266.523 us; speedup vs baseline: 1.3339x; 1.1867x over previous
//
#include <hip/hip_runtime.h>
#include <stdint.h>

#define NROW 8192
#define MCOL 8192
#define DH 64

// scale * log2(e): softmax computed as exp2(s * SC2) / sum
#define SC2 0.18033688011112042f

typedef __attribute__((ext_vector_type(8))) short short8;   // 8 bf16 (4 VGPRs)
typedef __attribute__((ext_vector_type(4))) short bf16x4;   // 4 bf16 (2 VGPRs)
typedef __attribute__((ext_vector_type(4))) float f32x4;
typedef __attribute__((ext_vector_type(4))) int   i32x4;

__device__ __forceinline__ short8 ldb8(const uint16_t* p) {
    return *reinterpret_cast<const short8*>(p);
}

__device__ __forceinline__ uint16_t f2bf(float f) {
    uint32_t u = __builtin_bit_cast(uint32_t, f);
    uint32_t r = (u + 0x7fffu + ((u >> 16) & 1u)) >> 16;
    return (uint16_t)r;
}

__device__ __forceinline__ float bf2f(uint16_t u) {
    return __builtin_bit_cast(float, (uint32_t)u << 16);
}

// ---------------- k_prep: Q,K -> bf16 ; V -> bf16 transposed Vt[d][c] ---------
__global__ __launch_bounds__(256) void k_prep(const float* __restrict__ Q,
                                              const float* __restrict__ K,
                                              const float* __restrict__ V,
                                              uint16_t* __restrict__ Qb,
                                              uint16_t* __restrict__ Kb,
                                              uint16_t* __restrict__ Vt) {
    int b = blockIdx.x, t = threadIdx.x;
    if (b < 128) {
        // transpose V rows [c0, c0+64) into Vt[dv][c]
        __shared__ float tile[64][65];
        int c0 = b * 64;
#pragma unroll
        for (int it = 0; it < 4; ++it) {
            int r = it * 16 + (t >> 4);
            int col = (t & 15) * 4;
            f32x4 v = *reinterpret_cast<const f32x4*>(V + (size_t)(c0 + r) * DH + col);
            tile[r][col + 0] = v[0]; tile[r][col + 1] = v[1];
            tile[r][col + 2] = v[2]; tile[r][col + 3] = v[3];
        }
        __syncthreads();
        int dv = t >> 2, cs = (t & 3) * 16;
        short8 o0, o1;
#pragma unroll
        for (int i = 0; i < 8; ++i) o0[i] = (short)f2bf(tile[cs + i][dv]);
#pragma unroll
        for (int i = 0; i < 8; ++i) o1[i] = (short)f2bf(tile[cs + 8 + i][dv]);
        *reinterpret_cast<short8*>(Vt + (size_t)dv * MCOL + c0 + cs) = o0;
        *reinterpret_cast<short8*>(Vt + (size_t)dv * MCOL + c0 + cs + 8) = o1;
    } else {
        const float* src; uint16_t* dst; int base;
        if (b < 640) { base = (b - 128) * 1024 + t * 4; src = Q; dst = Qb; }
        else         { base = (b - 640) * 1024 + t * 4; src = K; dst = Kb; }
        f32x4 v = *reinterpret_cast<const f32x4*>(src + base);
        uint64_t pk = (uint64_t)f2bf(v[0]) | ((uint64_t)f2bf(v[1]) << 16) |
                      ((uint64_t)f2bf(v[2]) << 32) | ((uint64_t)f2bf(v[3]) << 48);
        *reinterpret_cast<uint64_t*>(dst + base) = pk;
    }
}

// ---------------- k_pass1: row sums of masked exp + mask bit-packing ----------
// 4-wave blocks, per-wave K loads (K is L2-resident); vectorized int4 mask read.
__global__ __launch_bounds__(256, 8) void k_pass1(const uint16_t* __restrict__ Qb,
                                               const uint16_t* __restrict__ Kb,
                                               const int* __restrict__ mask,
                                               unsigned long long* __restrict__ pm2,
                                               float* __restrict__ lpart,
                                               int nstrip, int write_pm) {
    __shared__ unsigned long long rmask[4][16];
    int b = blockIdx.x + gridDim.x * blockIdx.y;
    int rb, s;
    if (nstrip == 16) {    // XCD-aware: xcd = b&7 owns strips {2*xcd, 2*xcd+1}
        int idx = b >> 3;
        s = (b & 7) * 2 + (idx >> 7);
        rb = idx & 127;
    } else { rb = blockIdx.x; s = blockIdx.y; }
    int t = threadIdx.x, lane = t & 63, w = t >> 6;
    int rw = rb * 64 + w * 16;
    int li = lane & 15, g = lane >> 4;

    const uint16_t* qbase = Qb + (size_t)(rw + li) * DH + g * 8;
    short8 qa0 = ldb8(qbase), qa1 = ldb8(qbase + 32);

    float rs[4] = {0.f, 0.f, 0.f, 0.f};
    int steps = 128 / nstrip;

    for (int ccl = 0; ccl < steps; ++ccl) {
        int cc = s * steps + ccl;
        int c0 = cc * 64;
        // mask: 4x int4 per lane covers 16 rows x 64 cols; pack to u64/row
#pragma unroll
        for (int it = 0; it < 4; ++it) {
            const i32x4* mp = reinterpret_cast<const i32x4*>(
                &mask[(size_t)(rw + it * 4 + g) * MCOL + c0 + li * 4]);
            i32x4 mv = __builtin_nontemporal_load(mp);
            uint32_t nib = (mv[0] != 0 ? 1u : 0u) | (mv[1] != 0 ? 2u : 0u) |
                           (mv[2] != 0 ? 4u : 0u) | (mv[3] != 0 ? 8u : 0u);
            unsigned long long rm = (unsigned long long)nib << (li * 4);
            rm |= __shfl_xor(rm, 1);
            rm |= __shfl_xor(rm, 2);
            rm |= __shfl_xor(rm, 4);
            rm |= __shfl_xor(rm, 8);
            if (li == 0) rmask[w][it * 4 + g] = rm;   // row it*4+g
        }
        // same-wave LDS write->read: compiler inserts lgkmcnt, no barrier needed
        if (write_pm && lane < 16)
            pm2[(size_t)cc * NROW + rw + lane] = rmask[w][lane];
        unsigned long long w64[4];
#pragma unroll
        for (int j = 0; j < 4; ++j) w64[j] = rmask[w][g * 4 + j];

#pragma unroll
        for (int ct = 0; ct < 4; ++ct) {
            const uint16_t* kbase = Kb + (size_t)(c0 + ct * 16 + li) * DH + g * 8;
            short8 kb0 = ldb8(kbase), kb1 = ldb8(kbase + 32);
            f32x4 acc = {0.f, 0.f, 0.f, 0.f};
            acc = __builtin_amdgcn_mfma_f32_16x16x32_bf16(qa0, kb0, acc, 0, 0, 0);
            acc = __builtin_amdgcn_mfma_f32_16x16x32_bf16(qa1, kb1, acc, 0, 0, 0);
            int bi = ct * 16 + li;
#pragma unroll
            for (int j = 0; j < 4; ++j) {
                if (!((w64[j] >> bi) & 1ull))
                    rs[j] += __builtin_amdgcn_exp2f(acc[j] * SC2);
            }
        }
    }
    // reduce across the 16 lanes of each group (cols), write per-strip partials
#pragma unroll
    for (int j = 0; j < 4; ++j) {
        rs[j] += __shfl_xor(rs[j], 1);
        rs[j] += __shfl_xor(rs[j], 2);
        rs[j] += __shfl_xor(rs[j], 4);
        rs[j] += __shfl_xor(rs[j], 8);
    }
    if (li == 0) {
        f32x4 o = {rs[0], rs[1], rs[2], rs[3]};
        *reinterpret_cast<f32x4*>(lpart + (size_t)s * NROW + rw + g * 4) = o;
    }
}

// swizzled LDS chunk layout: element (row, u16col) lives at
//   u16 index row*64 + (u16col ^ ((row&7)<<3))          [byte ^= (row&7)<<4]
// stage: thread t (512 threads) writes 16B: row=t>>3, bytecol=(t&7)<<4.

// ---------------- k_pass2: probs + context partials ---------------------------
__global__ __launch_bounds__(512, 8) void k_pass2(const uint16_t* __restrict__ Qb,
                                               const uint16_t* __restrict__ Kb,
                                               const uint16_t* __restrict__ Vt,
                                               const unsigned long long* __restrict__ pm2,
                                               const float* __restrict__ lpart,
                                               float* __restrict__ out_prob,
                                               float* __restrict__ ctx_out,
                                               int nstrip) {
    __shared__ uint16_t ks[4096];      // K-chunk, XOR-swizzled
    __shared__ uint16_t vs[4096];      // Vt-chunk [d][c], XOR-swizzled
    __shared__ uint16_t pt[8][1024];   // per-wave 16x64 bf16 P, XOR-swizzled
    int b = blockIdx.x + gridDim.x * blockIdx.y;
    int rb, s;
    if (nstrip == 16) {    // XCD-aware: xcd = b&7 owns strips {2*xcd, 2*xcd+1}
        int idx = b >> 3;
        s = (b & 7) * 2 + (idx >> 6);
        rb = idx & 63;
    } else { rb = blockIdx.x; s = blockIdx.y; }
    int t = threadIdx.x, lane = t & 63, w = t >> 6;
    int rw = rb * 128 + w * 16;
    int li = lane & 15, g = lane >> 4;

    int srow = t >> 3;
    int scol = ((t & 7) << 3) ^ ((srow & 7) << 3);

    // 1/l for this group's 4 rows (sum strip partials)
    f32x4 lsum = {0.f, 0.f, 0.f, 0.f};
    for (int s2 = 0; s2 < nstrip; ++s2)
        lsum += *reinterpret_cast<const f32x4*>(lpart + (size_t)s2 * NROW + rw + g * 4);
    float rinv[4];
#pragma unroll
    for (int j = 0; j < 4; ++j) rinv[j] = 1.0f / lsum[j];

    const uint16_t* qbase = Qb + (size_t)(rw + li) * DH + g * 8;
    short8 qa0 = ldb8(qbase), qa1 = ldb8(qbase + 32);

    f32x4 ctx[4];
#pragma unroll
    for (int dt = 0; dt < 4; ++dt) ctx[dt] = (f32x4){0.f, 0.f, 0.f, 0.f};

    int steps = 128 / nstrip;
    for (int ccl = 0; ccl < steps; ++ccl) {
        int cc = s * steps + ccl;
        int c0 = cc * 64;
        // stage K and V chunks (16B each per thread)
        short8 kv = ldb8(Kb + (size_t)(c0 + srow) * DH + scol);
        short8 vv = ldb8(Vt + (size_t)srow * MCOL + c0 + scol);
        unsigned long long w64[4];
        const unsigned long long* pmr = pm2 + (size_t)cc * NROW + rw;
#pragma unroll
        for (int j = 0; j < 4; ++j) w64[j] = pmr[g * 4 + j];

        __syncthreads();   // prior chunk fully consumed
        *reinterpret_cast<short8*>(&ks[t * 8]) = kv;
        *reinterpret_cast<short8*>(&vs[t * 8]) = vv;
        __syncthreads();   // chunks staged

#pragma unroll
        for (int ct = 0; ct < 4; ++ct) {
            int r = ct * 16 + li;
            short8 kb0 = ldb8(&ks[r * 64 + ((g * 8) ^ ((li & 7) << 3))]);
            short8 kb1 = ldb8(&ks[r * 64 + ((32 + g * 8) ^ ((li & 7) << 3))]);
            f32x4 acc = {0.f, 0.f, 0.f, 0.f};
            acc = __builtin_amdgcn_mfma_f32_16x16x32_bf16(qa0, kb0, acc, 0, 0, 0);
            acc = __builtin_amdgcn_mfma_f32_16x16x32_bf16(qa1, kb1, acc, 0, 0, 0);
            int bi = ct * 16 + li;
#pragma unroll
            for (int j = 0; j < 4; ++j) {
                int m = g * 4 + j;
                int bit = (int)((w64[j] >> bi) & 1ull);
                float p = bit ? 0.0f : __builtin_amdgcn_exp2f(acc[j] * SC2) * rinv[j];
                int e = ((m << 6) + bi) ^ ((m & 7) << 3);
                pt[w][e] = f2bf(p);
            }
        }
        // prob store: read bf16 P-tile back, convert, coalesced NT float4 stores
#pragma unroll
        for (int it = 0; it < 4; ++it) {
            int m = it * 4 + g;          // row 0..15
            int cb = li * 4;             // col base, multiple of 4
            int e = (m << 6) + (cb ^ ((m & 7) << 3));
            bf16x4 raw = *reinterpret_cast<const bf16x4*>(&pt[w][e]);
            f32x4 o;
            o[0] = bf2f((uint16_t)raw[0]);
            o[1] = bf2f((uint16_t)raw[1]);
            o[2] = bf2f((uint16_t)raw[2]);
            o[3] = bf2f((uint16_t)raw[3]);
            __builtin_nontemporal_store(
                o, reinterpret_cast<f32x4*>(&out_prob[(size_t)(rw + m) * MCOL + c0 + cb]));
        }
        // PV: context += P(16x64) * V(64x64), both operands from LDS
#pragma unroll
        for (int kc = 0; kc < 2; ++kc) {
            int eidx = ((li << 6) + kc * 32 + (g << 3)) ^ ((li & 7) << 3);
            short8 pa = *reinterpret_cast<const short8*>(&pt[w][eidx]);
#pragma unroll
            for (int dt = 0; dt < 4; ++dt) {
                int d = dt * 16 + li;
                short8 bv = ldb8(&vs[d * 64 + ((kc * 32 + g * 8) ^ ((li & 7) << 3))]);
                ctx[dt] = __builtin_amdgcn_mfma_f32_16x16x32_bf16(pa, bv, ctx[dt], 0, 0, 0);
            }
        }
    }
    // write context partial for this strip (stream-once -> NT)
    float* cbase = ctx_out + (size_t)s * NROW * DH;
#pragma unroll
    for (int dt = 0; dt < 4; ++dt)
#pragma unroll
        for (int j = 0; j < 4; ++j)
            __builtin_nontemporal_store(
                ctx[dt][j], &cbase[(size_t)(rw + g * 4 + j) * DH + dt * 16 + li]);
}

// ---------------- k_red: reduce context strip partials ------------------------
__global__ __launch_bounds__(256) void k_red(const float* __restrict__ cpart,
                                             float* __restrict__ out, int nstrip) {
    int i = blockIdx.x * 256 + threadIdx.x;   // 524288 total
    float a = 0.f;
    for (int s = 0; s < nstrip; ++s)
        a += __builtin_nontemporal_load(&cpart[(size_t)s * (NROW * DH) + i]);
    out[i] = a;
}

extern "C" void kernel_launch(void* const* d_in, const int* in_sizes, int n_in,
                              void* d_out, int out_size, void* d_ws, size_t ws_size,
                              hipStream_t stream) {
    const float* Q = (const float*)d_in[0];
    const float* K = (const float*)d_in[1];
    const float* V = (const float*)d_in[2];
    const int* mask = (const int*)d_in[3];

    float* out_ctx = (float*)d_out;
    float* out_prob = out_ctx + (size_t)NROW * DH;
    char* ws = (char*)d_ws;

    uint16_t* Qb = (uint16_t*)(ws);
    uint16_t* Kb = (uint16_t*)(ws + (1u << 20));
    uint16_t* Vt = (uint16_t*)(ws + (2u << 20));
    float* lpart = (float*)(ws + (3u << 20));          // up to 16 strips x 32 KB
    size_t off_pm = (3u << 20) + (1u << 19);           // 3.5 MB
    unsigned long long* pm2 = (unsigned long long*)(ws + off_pm);
    size_t pm_bytes = (size_t)128 * NROW * 8;          // 8 MB
    size_t off_ctx = off_pm + pm_bytes;                // 11.5 MB
    size_t ctx_strip = (size_t)NROW * DH * 4;          // 2 MB per strip

    int nstrip; float* ctx_out;
    if (ws_size >= off_ctx + 16 * ctx_strip)      { nstrip = 16; ctx_out = (float*)(ws + off_ctx); }
    else if (ws_size >= off_ctx + 8 * ctx_strip)  { nstrip = 8;  ctx_out = (float*)(ws + off_ctx); }
    else                                          { nstrip = 1;  ctx_out = out_ctx; }

    k_prep<<<dim3(1152), dim3(256), 0, stream>>>(Q, K, V, Qb, Kb, Vt);
    k_pass1<<<dim3(128, nstrip), dim3(256), 0, stream>>>(Qb, Kb, mask, pm2, lpart,
                                                         nstrip, 1);
    k_pass2<<<dim3(64, nstrip), dim3(512), 0, stream>>>(
        Qb, Kb, Vt, pm2, lpart, out_prob, ctx_out, nstrip);
    if (nstrip > 1)
        k_red<<<dim3(2048), dim3(256), 0, stream>>>(ctx_out, out_ctx, nstrip);
}